// Round 9
// baseline (18.102 us; speedup 1.0000x reference)
//
#include <hip/hip_runtime.h>

// SplatGaussian2D round 9: precomputed packed params (one dispatch, accurate
// trig) + RC=8 queue-compaction main. Light test: q = A vx^2 + B vx vy + C vy^2
// from packed [mx,my,A,B],[C,l2op,cs,sn]. Heavy phase reads only the pack.

constexpr int   BN    = 8192;
constexpr int   NG    = 2048;
constexpr float SMIN  = 1.0f / 30.0f;
constexpr float SSPAN = (1.0f / 0.75f - 1.0f / 30.0f);
constexpr float MUSCALE = 1.05f * 256.0f;
constexpr float LOG2E = 1.44269504088896341f;
constexpr float QT    = 25.0f * 1.44269504088896341f;
constexpr float TWOPI = 6.283185307179586f;
constexpr int   BLOCK = 256;
constexpr int   RC    = 8;               // rays per block
constexpr int   NBLK  = BN / RC;         // 1024 blocks
constexpr int   GPT   = NG / BLOCK;      // 8 k-steps
constexpr int   QMAX  = 2048;

__global__ __launch_bounds__(256) void splat_pre(
    const float* __restrict__ xyz, const float* __restrict__ opac,
    const float* __restrict__ scal, const float* __restrict__ rot,
    float* __restrict__ gp)              // [NG, 8]
{
    const int g = blockIdx.x * 256 + threadIdx.x;
    if (g >= NG) return;
    const float2 xy = reinterpret_cast<const float2*>(xyz)[g];
    const float2 sc = reinterpret_cast<const float2*>(scal)[g];
    const float  rr = rot[g];
    const float  op = fminf(fmaxf(opac[g], 0.0f), 1.0f);
    const float mx = fminf(fmaxf(xy.x, -1.0f), 1.0f) * MUSCALE;
    const float my = fminf(fmaxf(xy.y, -1.0f), 1.0f) * MUSCALE;
    const float s0 = fminf(fmaxf(sc.x, 0.0f), 1.0f) * SSPAN + SMIN;
    const float s1 = fminf(fmaxf(sc.y, 0.0f), 1.0f) * SSPAN + SMIN;
    const float ang = (rr - floorf(rr)) * TWOPI;
    const float cs = cosf(ang);
    const float sn = sinf(ang);
    const float qsx = s0 * s0 * LOG2E;
    const float qsy = s1 * s1 * LOG2E;
    const float c2 = cs * cs, s2 = sn * sn;
    const float A  = fmaf(qsx, c2, qsy * s2);
    const float C  = fmaf(qsx, s2, qsy * c2);
    const float Bq = 2.0f * cs * sn * (qsy - qsx);
    const float l2op = log2f(fmaxf(op, 1e-30f));
    float4* o = reinterpret_cast<float4*>(gp + 8 * g);
    o[0] = make_float4(mx, my, A, Bq);
    o[1] = make_float4(C, l2op, cs, sn);
}

__global__ __launch_bounds__(BLOCK) void splat_main(
    const float* __restrict__ xb,    // [B,2]
    const float* __restrict__ gp,    // [NG,8]
    const float* __restrict__ feat,  // [N,9,3]
    float* __restrict__ out)         // [B,3]
{
    __shared__ float    sray[RC * 2];
    __shared__ float    sacc[RC * 3];
    __shared__ unsigned queue[QMAX];
    __shared__ int      qcnt;

    const int tid = threadIdx.x;
    const int rc  = blockIdx.x;

    if (tid == 0) qcnt = 0;
    if (tid < RC) {
        const float2 t = reinterpret_cast<const float2*>(xb)[rc * RC + tid];
        sray[2 * tid + 0] = t.x - 256.0f;
        sray[2 * tid + 1] = t.y - 256.0f;
    }
    if (tid < RC * 3) sacc[tid] = 0.0f;
    __syncthreads();

    float rxs[RC], rys[RC];
    #pragma unroll
    for (int i = 0; i < RC; ++i) { rxs[i] = sray[2 * i]; rys[i] = sray[2 * i + 1]; }

    const float4* __restrict__ gp4 = reinterpret_cast<const float4*>(gp);

    // ---- light phase: depth-1 pipelined pack loads, 6-op test per pair ----
    float4 p0 = gp4[2 * tid + 0];
    for (int k = 0; k < GPT; ++k) {
        float4 n0;
        if (k + 1 < GPT) n0 = gp4[2 * ((k + 1) * BLOCK + tid)];
        const float mx = p0.x, my = p0.y, A = p0.z, Bq = p0.w;
        const float C  = gp4[2 * (k * BLOCK + tid) + 1].x;   // one extra dword
        const unsigned gbase = (unsigned)(k * BLOCK + tid) << 3;
        #pragma unroll
        for (int i = 0; i < RC; ++i) {
            const float vx = rxs[i] - mx;
            const float vy = rys[i] - my;
            const float q  = fmaf(A, vx * vx, fmaf(Bq, vx * vy, C * (vy * vy)));
            if (q < QT) {
                const int idx = atomicAdd(&qcnt, 1);
                if (idx < QMAX) queue[idx] = gbase | (unsigned)i;
            }
        }
        p0 = n0;
    }
    __syncthreads();

    // ---- heavy phase: one valid pair per lane, all params from the pack ----
    const int n = min(qcnt, QMAX);
    for (int j = tid; j < n; j += BLOCK) {
        const unsigned e = queue[j];
        const int g = (int)(e >> 3);
        const int i = (int)(e & 7u);

        const float4 a = gp4[2 * g + 0];   // mx,my,A,B
        const float4 b = gp4[2 * g + 1];   // C,l2op,cs,sn
        const float vx = sray[2 * i + 0] - a.x;
        const float vy = sray[2 * i + 1] - a.y;
        const float q  = fmaf(a.z, vx * vx, fmaf(a.w, vx * vy, b.x * (vy * vy)));
        const float w  = exp2f(b.y - q);
        const float cs = b.z, sn = b.w;
        const float rx = fmaf(cs, vx, -sn * vy);
        const float ry = fmaf(sn, vx,  cs * vy);

        const float iv  = rsqrtf(fmaxf(vx * vx + vy * vy, 1e-24f));
        const float s1v = rx * iv;
        const float c1v = ry * iv;
        const float s2v = 2.0f * s1v * c1v;
        const float c2v = fmaf(-2.0f * s1v, s1v, 1.0f);
        const float s3v = fmaf(s1v, c2v, c1v * s2v);
        const float c3v = fmaf(c1v, c2v, -s1v * s2v);
        const float s4v = 2.0f * s2v * c2v;
        const float c4v = fmaf(-2.0f * s2v, s2v, 1.0f);

        const float* __restrict__ fg = feat + (size_t)g * 27;
        float x0 = fg[0], x1 = fg[1], x2 = fg[2];
        x0 = fmaf(s1v, fg[3],  x0); x1 = fmaf(s1v, fg[4],  x1); x2 = fmaf(s1v, fg[5],  x2);
        x0 = fmaf(c1v, fg[6],  x0); x1 = fmaf(c1v, fg[7],  x1); x2 = fmaf(c1v, fg[8],  x2);
        x0 = fmaf(s2v, fg[9],  x0); x1 = fmaf(s2v, fg[10], x1); x2 = fmaf(s2v, fg[11], x2);
        x0 = fmaf(c2v, fg[12], x0); x1 = fmaf(c2v, fg[13], x1); x2 = fmaf(c2v, fg[14], x2);
        x0 = fmaf(s3v, fg[15], x0); x1 = fmaf(s3v, fg[16], x1); x2 = fmaf(s3v, fg[17], x2);
        x0 = fmaf(c3v, fg[18], x0); x1 = fmaf(c3v, fg[19], x1); x2 = fmaf(c3v, fg[20], x2);
        x0 = fmaf(s4v, fg[21], x0); x1 = fmaf(s4v, fg[22], x1); x2 = fmaf(s4v, fg[23], x2);
        x0 = fmaf(c4v, fg[24], x0); x1 = fmaf(c4v, fg[25], x1); x2 = fmaf(c4v, fg[26], x2);

        atomicAdd(&sacc[3 * i + 0], __fdividef(w, 1.0f + exp2f(-x0 * LOG2E)));
        atomicAdd(&sacc[3 * i + 1], __fdividef(w, 1.0f + exp2f(-x1 * LOG2E)));
        atomicAdd(&sacc[3 * i + 2], __fdividef(w, 1.0f + exp2f(-x2 * LOG2E)));
    }
    __syncthreads();

    if (tid < RC * 3)
        out[rc * (RC * 3) + tid] = sacc[tid];
}

extern "C" void kernel_launch(void* const* d_in, const int* in_sizes, int n_in,
                              void* d_out, int out_size, void* d_ws, size_t ws_size,
                              hipStream_t stream) {
    const float* xb   = (const float*)d_in[0];
    const float* xyz  = (const float*)d_in[1];
    const float* feat = (const float*)d_in[2];
    const float* opac = (const float*)d_in[3];
    const float* scal = (const float*)d_in[4];
    const float* rot  = (const float*)d_in[5];
    float* out = (float*)d_out;
    float* gp  = (float*)d_ws;               // NG*8 floats = 64 KB

    splat_pre<<<dim3(NG / 256), dim3(256), 0, stream>>>(xyz, opac, scal, rot, gp);
    splat_main<<<dim3(NBLK), dim3(BLOCK), 0, stream>>>(xb, gp, feat, out);
}

// Round 10
// 17.075 us; speedup vs baseline: 1.0602x; 1.0602x over previous
//
#include <hip/hip_runtime.h>

// SplatGaussian2D round 10: R8 geometry (RC=4, 2048 blocks, 8 waves/SIMD) +
// R9 packed params, restructured into two fully-prefetchable streams so the
// light loop has NO unprefetched dependent loads.
//   lt4[g]  = {mx, my, A, B}   (light test + heavy)
//   cArr[g] = C                (light test, prefetchable scalar stream)
//   gpb4[g] = {C, l2op, cs, sn} (heavy only)

constexpr int   BN    = 8192;
constexpr int   NG    = 2048;
constexpr float SMIN  = 1.0f / 30.0f;
constexpr float SSPAN = (1.0f / 0.75f - 1.0f / 30.0f);
constexpr float MUSCALE = 1.05f * 256.0f;
constexpr float LOG2E = 1.44269504088896341f;
constexpr float QT    = 25.0f * 1.44269504088896341f;
constexpr float TWOPI = 6.283185307179586f;
constexpr int   BLOCK = 256;
constexpr int   RC    = 4;               // rays per block
constexpr int   NBLK  = BN / RC;         // 2048 blocks -> 8 blocks/CU
constexpr int   GPT   = NG / BLOCK;      // 8 k-steps
constexpr int   QMAX  = 1024;

// ws float offsets
constexpr int WS_LT  = 0;                // float4[NG]
constexpr int WS_GPB = WS_LT + NG * 4;   // float4[NG]
constexpr int WS_C   = WS_GPB + NG * 4;  // float[NG]

__global__ __launch_bounds__(256) void splat_pre(
    const float* __restrict__ xyz, const float* __restrict__ opac,
    const float* __restrict__ scal, const float* __restrict__ rot,
    float* __restrict__ ws)
{
    const int g = blockIdx.x * 256 + threadIdx.x;
    if (g >= NG) return;
    const float2 xy = reinterpret_cast<const float2*>(xyz)[g];
    const float2 sc = reinterpret_cast<const float2*>(scal)[g];
    const float  rr = rot[g];
    const float  op = fminf(fmaxf(opac[g], 0.0f), 1.0f);
    const float mx = fminf(fmaxf(xy.x, -1.0f), 1.0f) * MUSCALE;
    const float my = fminf(fmaxf(xy.y, -1.0f), 1.0f) * MUSCALE;
    const float s0 = fminf(fmaxf(sc.x, 0.0f), 1.0f) * SSPAN + SMIN;
    const float s1 = fminf(fmaxf(sc.y, 0.0f), 1.0f) * SSPAN + SMIN;
    const float ang = (rr - floorf(rr)) * TWOPI;
    const float cs = cosf(ang);
    const float sn = sinf(ang);
    const float qsx = s0 * s0 * LOG2E;
    const float qsy = s1 * s1 * LOG2E;
    const float c2 = cs * cs, s2 = sn * sn;
    const float A  = fmaf(qsx, c2, qsy * s2);
    const float C  = fmaf(qsx, s2, qsy * c2);
    const float Bq = 2.0f * cs * sn * (qsy - qsx);
    const float l2op = log2f(fmaxf(op, 1e-30f));
    reinterpret_cast<float4*>(ws + WS_LT)[g]  = make_float4(mx, my, A, Bq);
    reinterpret_cast<float4*>(ws + WS_GPB)[g] = make_float4(C, l2op, cs, sn);
    ws[WS_C + g] = C;
}

__global__ __launch_bounds__(BLOCK) void splat_main(
    const float* __restrict__ xb,    // [B,2]
    const float* __restrict__ ws,    // packs
    const float* __restrict__ feat,  // [N,9,3]
    float* __restrict__ out)         // [B,3]
{
    __shared__ float    sray[RC * 2];
    __shared__ float    sacc[RC * 3];
    __shared__ unsigned queue[QMAX];
    __shared__ int      qcnt;

    const int tid = threadIdx.x;
    const int rc  = blockIdx.x;

    if (tid == 0) qcnt = 0;
    if (tid < RC) {
        const float2 t = reinterpret_cast<const float2*>(xb)[rc * RC + tid];
        sray[2 * tid + 0] = t.x - 256.0f;
        sray[2 * tid + 1] = t.y - 256.0f;
    }
    if (tid < RC * 3) sacc[tid] = 0.0f;
    __syncthreads();

    float rxs[RC], rys[RC];
    #pragma unroll
    for (int i = 0; i < RC; ++i) { rxs[i] = sray[2 * i]; rys[i] = sray[2 * i + 1]; }

    const float4* __restrict__ lt4  = reinterpret_cast<const float4*>(ws + WS_LT);
    const float4* __restrict__ gpb4 = reinterpret_cast<const float4*>(ws + WS_GPB);
    const float*  __restrict__ cArr = ws + WS_C;

    // ---- light phase: depth-1 prefetch of BOTH streams, 6-op test/pair ----
    float4 p0 = lt4[tid];
    float  c0 = cArr[tid];
    for (int k = 0; k < GPT; ++k) {
        float4 n0; float nc;
        if (k + 1 < GPT) {
            const int gn = (k + 1) * BLOCK + tid;
            n0 = lt4[gn];
            nc = cArr[gn];
        }
        const unsigned gbase = (unsigned)(k * BLOCK + tid) << 2;
        #pragma unroll
        for (int i = 0; i < RC; ++i) {
            const float vx = rxs[i] - p0.x;
            const float vy = rys[i] - p0.y;
            const float q  = fmaf(p0.z, vx * vx, fmaf(p0.w, vx * vy, c0 * (vy * vy)));
            if (q < QT) {
                const int idx = atomicAdd(&qcnt, 1);
                if (idx < QMAX) queue[idx] = gbase | (unsigned)i;
            }
        }
        p0 = n0; c0 = nc;
    }
    __syncthreads();

    // ---- heavy phase: one valid pair per lane, params from packs ----
    const int n = min(qcnt, QMAX);
    for (int j = tid; j < n; j += BLOCK) {
        const unsigned e = queue[j];
        const int g = (int)(e >> 2);
        const int i = (int)(e & 3u);

        const float4 a = lt4[g];            // mx,my,A,B
        const float4 b = gpb4[g];           // C,l2op,cs,sn
        const float vx = sray[2 * i + 0] - a.x;
        const float vy = sray[2 * i + 1] - a.y;
        const float q  = fmaf(a.z, vx * vx, fmaf(a.w, vx * vy, b.x * (vy * vy)));
        const float w  = exp2f(b.y - q);
        const float cs = b.z, sn = b.w;
        const float rx = fmaf(cs, vx, -sn * vy);
        const float ry = fmaf(sn, vx,  cs * vy);

        const float iv  = rsqrtf(fmaxf(vx * vx + vy * vy, 1e-24f));
        const float s1v = rx * iv;
        const float c1v = ry * iv;
        const float s2v = 2.0f * s1v * c1v;
        const float c2v = fmaf(-2.0f * s1v, s1v, 1.0f);
        const float s3v = fmaf(s1v, c2v, c1v * s2v);
        const float c3v = fmaf(c1v, c2v, -s1v * s2v);
        const float s4v = 2.0f * s2v * c2v;
        const float c4v = fmaf(-2.0f * s2v, s2v, 1.0f);

        const float* __restrict__ fg = feat + (size_t)g * 27;
        float x0 = fg[0], x1 = fg[1], x2 = fg[2];
        x0 = fmaf(s1v, fg[3],  x0); x1 = fmaf(s1v, fg[4],  x1); x2 = fmaf(s1v, fg[5],  x2);
        x0 = fmaf(c1v, fg[6],  x0); x1 = fmaf(c1v, fg[7],  x1); x2 = fmaf(c1v, fg[8],  x2);
        x0 = fmaf(s2v, fg[9],  x0); x1 = fmaf(s2v, fg[10], x1); x2 = fmaf(s2v, fg[11], x2);
        x0 = fmaf(c2v, fg[12], x0); x1 = fmaf(c2v, fg[13], x1); x2 = fmaf(c2v, fg[14], x2);
        x0 = fmaf(s3v, fg[15], x0); x1 = fmaf(s3v, fg[16], x1); x2 = fmaf(s3v, fg[17], x2);
        x0 = fmaf(c3v, fg[18], x0); x1 = fmaf(c3v, fg[19], x1); x2 = fmaf(c3v, fg[20], x2);
        x0 = fmaf(s4v, fg[21], x0); x1 = fmaf(s4v, fg[22], x1); x2 = fmaf(s4v, fg[23], x2);
        x0 = fmaf(c4v, fg[24], x0); x1 = fmaf(c4v, fg[25], x1); x2 = fmaf(c4v, fg[26], x2);

        atomicAdd(&sacc[3 * i + 0], __fdividef(w, 1.0f + exp2f(-x0 * LOG2E)));
        atomicAdd(&sacc[3 * i + 1], __fdividef(w, 1.0f + exp2f(-x1 * LOG2E)));
        atomicAdd(&sacc[3 * i + 2], __fdividef(w, 1.0f + exp2f(-x2 * LOG2E)));
    }
    __syncthreads();

    if (tid < RC * 3)
        out[rc * (RC * 3) + tid] = sacc[tid];
}

extern "C" void kernel_launch(void* const* d_in, const int* in_sizes, int n_in,
                              void* d_out, int out_size, void* d_ws, size_t ws_size,
                              hipStream_t stream) {
    const float* xb   = (const float*)d_in[0];
    const float* xyz  = (const float*)d_in[1];
    const float* feat = (const float*)d_in[2];
    const float* opac = (const float*)d_in[3];
    const float* scal = (const float*)d_in[4];
    const float* rot  = (const float*)d_in[5];
    float* out = (float*)d_out;
    float* ws  = (float*)d_ws;               // 72 KB of packs

    splat_pre<<<dim3(NG / 256), dim3(256), 0, stream>>>(xyz, opac, scal, rot, ws);
    splat_main<<<dim3(NBLK), dim3(BLOCK), 0, stream>>>(xb, ws, feat, out);
}

// Round 11
// 15.242 us; speedup vs baseline: 1.1877x; 1.1203x over previous
//
#include <hip/hip_runtime.h>
#include <hip/hip_fp16.h>

// SplatGaussian2D round 11: single dispatch. Block = 8 rays vs ALL gaussians.
// Per-block prep of f16-packed light-test params into LDS SoA (su0/su1/su2),
// conflict-free word-stride reads. Light test q = A vx^2 + B vx vy + C vy^2
// (f16 — only flips pairs at w~1e-10, harmless). Valid pairs -> LDS queue ->
// heavy phase recomputes exactly from raw f32 inputs (accurate trig).

constexpr int   BN    = 8192;
constexpr int   NG    = 2048;
constexpr float SMIN  = 1.0f / 30.0f;
constexpr float SSPAN = (1.0f / 0.75f - 1.0f / 30.0f);
constexpr float MUSCALE = 1.05f * 256.0f;
constexpr float LOG2E = 1.44269504088896341f;
constexpr float QT    = 25.0f * 1.44269504088896341f;
constexpr float TWOPI = 6.283185307179586f;
constexpr int   BLOCK = 256;
constexpr int   RC    = 8;               // rays per block
constexpr int   NBLK  = BN / RC;         // 1024 blocks -> 4 blocks/CU
constexpr int   GPT   = NG / BLOCK;      // 8
constexpr int   QMAX  = 2048;

static __device__ __forceinline__ unsigned pk2h(float a, float b) {
    __half2 h = __floats2half2_rn(a, b);
    return __builtin_bit_cast(unsigned, h);
}
static __device__ __forceinline__ float2 unpk(unsigned u) {
    __half2 h = __builtin_bit_cast(__half2, u);
    return __half22float2(h);
}

__global__ __launch_bounds__(BLOCK) void splat_one(
    const float* __restrict__ xb,   // [B,2]
    const float* __restrict__ xyz,  // [N,2]
    const float* __restrict__ feat, // [N,9,3]
    const float* __restrict__ opac, // [N]
    const float* __restrict__ scal, // [N,2]
    const float* __restrict__ rot,  // [N]
    float* __restrict__ out)        // [B,3]
{
    __shared__ unsigned su0[NG], su1[NG], su2[NG];   // {mx,my},{A,B},{C,-} f16
    __shared__ float    sray[RC * 2];
    __shared__ float    sacc[RC * 3];
    __shared__ unsigned queue[QMAX];
    __shared__ int      qcnt;

    const int tid = threadIdx.x;
    const int rc  = blockIdx.x;

    if (tid == 0) qcnt = 0;
    if (tid < RC) {
        const float2 t = reinterpret_cast<const float2*>(xb)[rc * RC + tid];
        sray[2 * tid + 0] = t.x - 256.0f;
        sray[2 * tid + 1] = t.y - 256.0f;
    }
    if (tid < RC * 3) sacc[tid] = 0.0f;

    // ---- prep: each thread packs GPT gaussians into LDS (coalesced loads) ----
    #pragma unroll
    for (int k = 0; k < GPT; ++k) {
        const int g = k * BLOCK + tid;
        const float2 xy = reinterpret_cast<const float2*>(xyz)[g];
        const float2 sc = reinterpret_cast<const float2*>(scal)[g];
        const float  rr = rot[g];
        const float mx = fminf(fmaxf(xy.x, -1.0f), 1.0f) * MUSCALE;
        const float my = fminf(fmaxf(xy.y, -1.0f), 1.0f) * MUSCALE;
        const float s0 = fminf(fmaxf(sc.x, 0.0f), 1.0f) * SSPAN + SMIN;
        const float s1 = fminf(fmaxf(sc.y, 0.0f), 1.0f) * SSPAN + SMIN;
        const float ang = (rr - floorf(rr)) * TWOPI;
        float sn, cs;
        __sincosf(ang, &sn, &cs);
        const float qsx = s0 * s0 * LOG2E;
        const float qsy = s1 * s1 * LOG2E;
        const float c2 = cs * cs, s2 = sn * sn;
        const float A  = fmaf(qsx, c2, qsy * s2);
        const float C  = fmaf(qsx, s2, qsy * c2);
        const float Bq = 2.0f * cs * sn * (qsy - qsx);
        su0[g] = pk2h(mx, my);
        su1[g] = pk2h(A, Bq);
        su2[g] = pk2h(C, 0.0f);
    }
    __syncthreads();

    float rxs[RC], rys[RC];
    #pragma unroll
    for (int i = 0; i < RC; ++i) { rxs[i] = sray[2 * i]; rys[i] = sray[2 * i + 1]; }

    // ---- light phase: LDS-resident f16 test, 8 rays per gaussian ----
    #pragma unroll
    for (int k = 0; k < GPT; ++k) {
        const int g = k * BLOCK + tid;
        const float2 m  = unpk(su0[g]);
        const float2 ab = unpk(su1[g]);
        const float2 cc = unpk(su2[g]);
        #pragma unroll
        for (int i = 0; i < RC; ++i) {
            const float vx = rxs[i] - m.x;
            const float vy = rys[i] - m.y;
            const float q  = fmaf(ab.x, vx * vx,
                             fmaf(ab.y, vx * vy, cc.x * (vy * vy)));
            if (q < QT) {
                const int idx = atomicAdd(&qcnt, 1);
                if (idx < QMAX) queue[idx] = ((unsigned)g << 3) | (unsigned)i;
            }
        }
    }
    __syncthreads();

    // ---- heavy phase: exact recompute from raw inputs, accurate trig ----
    const int n = min(qcnt, QMAX);
    for (int j = tid; j < n; j += BLOCK) {
        const unsigned e = queue[j];
        const int g = (int)(e >> 3);
        const int i = (int)(e & 7u);

        const float2 xy = reinterpret_cast<const float2*>(xyz)[g];
        const float2 sc = reinterpret_cast<const float2*>(scal)[g];
        const float  rr = rot[g];
        const float  op = fminf(fmaxf(opac[g], 0.0f), 1.0f);
        const float mx = fminf(fmaxf(xy.x, -1.0f), 1.0f) * MUSCALE;
        const float my = fminf(fmaxf(xy.y, -1.0f), 1.0f) * MUSCALE;
        const float s0 = fminf(fmaxf(sc.x, 0.0f), 1.0f) * SSPAN + SMIN;
        const float s1 = fminf(fmaxf(sc.y, 0.0f), 1.0f) * SSPAN + SMIN;
        const float ang = (rr - floorf(rr)) * TWOPI;
        const float cs = cosf(ang);
        const float sn = sinf(ang);

        const float vx = sray[2 * i + 0] - mx;
        const float vy = sray[2 * i + 1] - my;
        const float rx = fmaf(cs, vx, -sn * vy);
        const float ry = fmaf(sn, vx,  cs * vy);
        const float q  = fmaf(s0 * s0 * LOG2E, rx * rx,
                              (s1 * s1 * LOG2E) * (ry * ry));
        const float w  = exp2f(log2f(fmaxf(op, 1e-30f)) - q);

        const float iv  = rsqrtf(fmaxf(vx * vx + vy * vy, 1e-24f));
        const float s1v = rx * iv;
        const float c1v = ry * iv;
        const float s2v = 2.0f * s1v * c1v;
        const float c2v = fmaf(-2.0f * s1v, s1v, 1.0f);
        const float s3v = fmaf(s1v, c2v, c1v * s2v);
        const float c3v = fmaf(c1v, c2v, -s1v * s2v);
        const float s4v = 2.0f * s2v * c2v;
        const float c4v = fmaf(-2.0f * s2v, s2v, 1.0f);

        const float* __restrict__ fg = feat + (size_t)g * 27;
        float x0 = fg[0], x1 = fg[1], x2 = fg[2];
        x0 = fmaf(s1v, fg[3],  x0); x1 = fmaf(s1v, fg[4],  x1); x2 = fmaf(s1v, fg[5],  x2);
        x0 = fmaf(c1v, fg[6],  x0); x1 = fmaf(c1v, fg[7],  x1); x2 = fmaf(c1v, fg[8],  x2);
        x0 = fmaf(s2v, fg[9],  x0); x1 = fmaf(s2v, fg[10], x1); x2 = fmaf(s2v, fg[11], x2);
        x0 = fmaf(c2v, fg[12], x0); x1 = fmaf(c2v, fg[13], x1); x2 = fmaf(c2v, fg[14], x2);
        x0 = fmaf(s3v, fg[15], x0); x1 = fmaf(s3v, fg[16], x1); x2 = fmaf(s3v, fg[17], x2);
        x0 = fmaf(c3v, fg[18], x0); x1 = fmaf(c3v, fg[19], x1); x2 = fmaf(c3v, fg[20], x2);
        x0 = fmaf(s4v, fg[21], x0); x1 = fmaf(s4v, fg[22], x1); x2 = fmaf(s4v, fg[23], x2);
        x0 = fmaf(c4v, fg[24], x0); x1 = fmaf(c4v, fg[25], x1); x2 = fmaf(c4v, fg[26], x2);

        atomicAdd(&sacc[3 * i + 0], __fdividef(w, 1.0f + exp2f(-x0 * LOG2E)));
        atomicAdd(&sacc[3 * i + 1], __fdividef(w, 1.0f + exp2f(-x1 * LOG2E)));
        atomicAdd(&sacc[3 * i + 2], __fdividef(w, 1.0f + exp2f(-x2 * LOG2E)));
    }
    __syncthreads();

    if (tid < RC * 3)
        out[rc * (RC * 3) + tid] = sacc[tid];
}

extern "C" void kernel_launch(void* const* d_in, const int* in_sizes, int n_in,
                              void* d_out, int out_size, void* d_ws, size_t ws_size,
                              hipStream_t stream) {
    const float* xb   = (const float*)d_in[0];
    const float* xyz  = (const float*)d_in[1];
    const float* feat = (const float*)d_in[2];
    const float* opac = (const float*)d_in[3];
    const float* scal = (const float*)d_in[4];
    const float* rot  = (const float*)d_in[5];
    float* out = (float*)d_out;

    splat_one<<<dim3(NBLK), dim3(BLOCK), 0, stream>>>(
        xb, xyz, feat, opac, scal, rot, out);
}